// Round 1
// baseline (1865.820 us; speedup 1.0000x reference)
//
#include <hip/hip_runtime.h>
#include <math.h>

// Problem constants
constexpr int kN  = 50000;     // nodes
constexpr int kE  = 600000;    // raw edges
constexpr int kET = 650000;    // edges + self loops
constexpr int kG  = 50;        // graphs
constexpr int kH  = 4;         // heads

// ws layout (float offsets)
constexpr size_t OFF_HCUR  = 0;                       // N*64
constexpr size_t OFF_HNEXT = 3200000;                 // N*64
constexpr size_t OFF_HP    = 6400000;                 // N*256
constexpr size_t OFF_ES    = 19200000;                // N*4
constexpr size_t OFF_ED    = 19400000;                // N*4
constexpr size_t OFF_M     = 19600000;                // N*4 (uint-encoded max)
constexpr size_t OFF_S     = 19800000;                // N*4
constexpr size_t OFF_ALPHA = 20000000;                // ET*4
constexpr size_t OFF_BN    = 22600000;                // 2*64

// ---- float<->uint monotonic encoding for atomic max ----
__device__ inline unsigned enc_f(float f) {
    unsigned b = __float_as_uint(f);
    return (b & 0x80000000u) ? ~b : (b | 0x80000000u);
}
__device__ inline float dec_f(unsigned u) {
    return __uint_as_float((u & 0x80000000u) ? (u & 0x7FFFFFFFu) : ~u);
}

__device__ inline void edge_pair(const int* __restrict__ ei, int e, int& src, int& dst) {
    if (e < kE) { src = ei[e]; dst = ei[kE + e]; }
    else        { src = e - kE; dst = e - kE; }
}

// h0[n][c] = x[n][:5] @ enc_w[:, c] + enc_b[c]
__global__ void k_encoder(const float* __restrict__ x, const float* __restrict__ w,
                          const float* __restrict__ b, float* __restrict__ h) {
    int i = blockIdx.x * blockDim.x + threadIdx.x;
    if (i >= kN * 64) return;
    int n = i >> 6, c = i & 63;
    float acc = b[c];
#pragma unroll
    for (int k = 0; k < 5; ++k) acc += x[n * 5 + k] * w[k * 64 + c];
    h[i] = acc;
}

// hp[n][j] = h[n][:64] @ W[:, j]   (j in [0, HD))
template <int HD>
__global__ void k_linear(const float* __restrict__ h, const float* __restrict__ W,
                         float* __restrict__ hp) {
    int i = blockIdx.x * blockDim.x + threadIdx.x;
    if (i >= kN * HD) return;
    int n = i / HD, j = i % HD;
    const float* hr = h + n * 64;
    float acc = 0.f;
#pragma unroll 16
    for (int k = 0; k < 64; ++k) acc += hr[k] * W[k * HD + j];
    hp[i] = acc;
}

// es[n][h], ed[n][h] = sum_c hp[n][h][c] * a_{s,d}[h][c]
template <int DOUT>
__global__ void k_att(const float* __restrict__ hp, const float* __restrict__ a_s,
                      const float* __restrict__ a_d, float* __restrict__ es,
                      float* __restrict__ ed) {
    int i = blockIdx.x * blockDim.x + threadIdx.x;
    if (i >= kN * kH) return;
    int h = i & 3;
    const float* row = hp + (size_t)i * DOUT;  // (n*H + h) * DOUT
    float s1 = 0.f, s2 = 0.f;
#pragma unroll 8
    for (int c = 0; c < DOUT; ++c) {
        float v = row[c];
        s1 += v * a_s[h * DOUT + c];
        s2 += v * a_d[h * DOUT + c];
    }
    es[i] = s1;
    ed[i] = s2;
}

// segment max over dst of leaky_relu(es[src]+ed[dst])
__global__ void k_edge_max(const int* __restrict__ ei, const float* __restrict__ es,
                           const float* __restrict__ ed, unsigned* __restrict__ m) {
    int e = blockIdx.x * blockDim.x + threadIdx.x;
    if (e >= kET) return;
    int src, dst;
    edge_pair(ei, e, src, dst);
#pragma unroll
    for (int h = 0; h < kH; ++h) {
        float v = es[src * 4 + h] + ed[dst * 4 + h];
        v = (v >= 0.f) ? v : 0.2f * v;
        atomicMax(&m[dst * 4 + h], enc_f(v));
    }
}

// alpha[e][h] = exp(e - m[dst]);  s[dst][h] += alpha
__global__ void k_edge_sum(const int* __restrict__ ei, const float* __restrict__ es,
                           const float* __restrict__ ed, const unsigned* __restrict__ m,
                           float* __restrict__ alpha, float* __restrict__ s) {
    int e = blockIdx.x * blockDim.x + threadIdx.x;
    if (e >= kET) return;
    int src, dst;
    edge_pair(ei, e, src, dst);
#pragma unroll
    for (int h = 0; h < kH; ++h) {
        float v = es[src * 4 + h] + ed[dst * 4 + h];
        v = (v >= 0.f) ? v : 0.2f * v;
        float ex = expf(v - dec_f(m[dst * 4 + h]));
        alpha[e * 4 + h] = ex;
        atomicAdd(&s[dst * 4 + h], ex);
    }
}

// hnext[dst][c] += sum_h alpha/(s+1e-16) * 0.25 * hp[src][h][c]
template <int DOUT>
__global__ void k_edge_agg(const int* __restrict__ ei, const float* __restrict__ alpha,
                           const float* __restrict__ s, const float* __restrict__ hp,
                           float* __restrict__ hnext) {
    int idx = blockIdx.x * blockDim.x + threadIdx.x;
    int e = idx / DOUT;
    int c = idx % DOUT;
    if (e >= kET) return;
    int src, dst;
    edge_pair(ei, e, src, dst);
    float acc = 0.f;
#pragma unroll
    for (int h = 0; h < kH; ++h) {
        float w = alpha[e * 4 + h] / (s[dst * 4 + h] + 1e-16f) * 0.25f;
        acc += w * hp[((size_t)src * kH + h) * DOUT + c];
    }
    atomicAdd(&hnext[dst * DOUT + c], acc);
}

// per-channel sum and sumsq over nodes
template <int DOUT>
__global__ void k_bn_stats(const float* __restrict__ h, float* __restrict__ bn) {
    constexpr int ROWS = 256 / DOUT;
    __shared__ float ls[256], lq[256];
    int c = threadIdx.x % DOUT;
    int r = threadIdx.x / DOUT;
    float s = 0.f, q = 0.f;
    for (int n = blockIdx.x * ROWS + r; n < kN; n += gridDim.x * ROWS) {
        float v = h[n * DOUT + c];
        s += v;
        q += v * v;
    }
    ls[threadIdx.x] = s;
    lq[threadIdx.x] = q;
    __syncthreads();
    if (r == 0) {
#pragma unroll
        for (int i = 1; i < ROWS; ++i) {
            s += ls[i * DOUT + c];
            q += lq[i * DOUT + c];
        }
        atomicAdd(&bn[c], s);
        atomicAdd(&bn[DOUT + c], q);
    }
}

template <int DOUT, bool RELU>
__global__ void k_bn_apply(const float* __restrict__ h, const float* __restrict__ bn,
                           const float* __restrict__ g, const float* __restrict__ be,
                           float* __restrict__ out) {
    int i = blockIdx.x * blockDim.x + threadIdx.x;
    if (i >= kN * DOUT) return;
    int c = i % DOUT;
    float mu = bn[c] * (1.f / kN);
    float var = bn[DOUT + c] * (1.f / kN) - mu * mu;
    float v = g[c] * (h[i] - mu) * rsqrtf(var + 1e-5f) + be[c];
    if (RELU) v = fmaxf(v, 0.f);
    out[i] = v;
}

// per-graph pooling: batch sorted -> binary-search boundaries, block reduce
__global__ void k_pool(const float* __restrict__ h, const int* __restrict__ batch,
                       float* __restrict__ gemb) {
    int g = blockIdx.x;
    int lo = 0, hi = kN;
    while (lo < hi) { int mid = (lo + hi) >> 1; if (batch[mid] < g) lo = mid + 1; else hi = mid; }
    int start = lo;
    lo = start; hi = kN;
    while (lo < hi) { int mid = (lo + hi) >> 1; if (batch[mid] < g + 1) lo = mid + 1; else hi = mid; }
    int end = lo;

    int c = threadIdx.x & 31, r = threadIdx.x >> 5;  // 8 rows x 32 channels
    float sum = 0.f, mx = -INFINITY;
    for (int n = start + r; n < end; n += 8) {
        float v = h[n * 32 + c];
        sum += v;
        mx = fmaxf(mx, v);
    }
    __shared__ float ssum[256], smax[256];
    ssum[threadIdx.x] = sum;
    smax[threadIdx.x] = mx;
    __syncthreads();
    if (r == 0) {
#pragma unroll
        for (int i = 1; i < 8; ++i) {
            sum += ssum[i * 32 + c];
            mx = fmaxf(mx, smax[i * 32 + c]);
        }
        int cnt = end - start;
        float mean = sum / fmaxf((float)cnt, 1.f);
        if (cnt <= 0) mx = 0.f;
        gemb[g * 32 + c] = (mean + mx + sum) * (1.f / 3.f);
    }
}

__global__ void k_heads(const float* __restrict__ gemb, const float* __restrict__ ew1,
                        const float* __restrict__ eb1, const float* __restrict__ ew2,
                        const float* __restrict__ eb2, const float* __restrict__ mw1,
                        const float* __restrict__ mb1, const float* __restrict__ mw2,
                        const float* __restrict__ mb2, float* __restrict__ eth,
                        float* __restrict__ man) {
    int g = blockIdx.x * blockDim.x + threadIdx.x;
    if (g >= kG) return;
    const float* row = gemb + g * 32;
    float acc_e = eb2[0], acc_m = mb2[0];
#pragma unroll 4
    for (int j = 0; j < 16; ++j) {
        float he = eb1[j], hm = mb1[j];
        for (int k = 0; k < 32; ++k) {
            float v = row[k];
            he += v * ew1[k * 16 + j];
            hm += v * mw1[k * 16 + j];
        }
        acc_e += fmaxf(he, 0.f) * ew2[j];
        acc_m += fmaxf(hm, 0.f) * mw2[j];
    }
    eth[g] = 1.f / (1.f + expf(-acc_e));
    man[g] = 1.f / (1.f + expf(-acc_m));
}

extern "C" void kernel_launch(void* const* d_in, const int* in_sizes, int n_in,
                              void* d_out, int out_size, void* d_ws, size_t ws_size,
                              hipStream_t stream) {
    const float* x     = (const float*)d_in[0];
    const int*   ei    = (const int*)d_in[1];
    const int*   batch = (const int*)d_in[2];
    const float* enc_w = (const float*)d_in[3];
    const float* enc_b = (const float*)d_in[4];

    float* ws = (float*)d_ws;
    float*    hcur  = ws + OFF_HCUR;
    float*    hnext = ws + OFF_HNEXT;
    float*    hp    = ws + OFF_HP;
    float*    es    = ws + OFF_ES;
    float*    ed    = ws + OFF_ED;
    unsigned* m     = (unsigned*)(ws + OFF_M);
    float*    sden  = ws + OFF_S;
    float*    alpha = ws + OFF_ALPHA;
    float*    bn    = ws + OFF_BN;

    float* out      = (float*)d_out;
    float* out_h    = out;                 // N*32
    float* out_gemb = out + 1600000;       // G*32
    float* out_eth  = out + 1601600;       // G
    float* out_man  = out + 1601650;       // G

    k_encoder<<<(kN * 64 + 255) / 256, 256, 0, stream>>>(x, enc_w, enc_b, hcur);

    for (int l = 0; l < 3; ++l) {
        const int dout = (l == 2) ? 32 : 64;
        const float* W    = (const float*)d_in[5 + 6 * l];
        const float* a_s  = (const float*)d_in[6 + 6 * l];
        const float* a_d  = (const float*)d_in[7 + 6 * l];
        const float* gam  = (const float*)d_in[9 + 6 * l];
        const float* bet  = (const float*)d_in[10 + 6 * l];

        if (dout == 64) {
            k_linear<256><<<(kN * 256 + 255) / 256, 256, 0, stream>>>(hcur, W, hp);
            k_att<64><<<(kN * kH + 255) / 256, 256, 0, stream>>>(hp, a_s, a_d, es, ed);
        } else {
            k_linear<128><<<(kN * 128 + 255) / 256, 256, 0, stream>>>(hcur, W, hp);
            k_att<32><<<(kN * kH + 255) / 256, 256, 0, stream>>>(hp, a_s, a_d, es, ed);
        }

        hipMemsetAsync(m, 0, kN * kH * sizeof(unsigned), stream);
        hipMemsetAsync(sden, 0, kN * kH * sizeof(float), stream);
        hipMemsetAsync(hnext, 0, kN * dout * sizeof(float), stream);
        hipMemsetAsync(bn, 0, 2 * 64 * sizeof(float), stream);

        k_edge_max<<<(kET + 255) / 256, 256, 0, stream>>>(ei, es, ed, m);
        k_edge_sum<<<(kET + 255) / 256, 256, 0, stream>>>(ei, es, ed, m, alpha, sden);

        if (dout == 64) {
            k_edge_agg<64><<<(kET * 64 + 255) / 256, 256, 0, stream>>>(ei, alpha, sden, hp, hnext);
            k_bn_stats<64><<<128, 256, 0, stream>>>(hnext, bn);
            if (l < 2)
                k_bn_apply<64, true><<<(kN * 64 + 255) / 256, 256, 0, stream>>>(hnext, bn, gam, bet, hcur);
            else
                k_bn_apply<64, false><<<(kN * 64 + 255) / 256, 256, 0, stream>>>(hnext, bn, gam, bet, hcur);
        } else {
            k_edge_agg<32><<<(kET * 32 + 255) / 256, 256, 0, stream>>>(ei, alpha, sden, hp, hnext);
            k_bn_stats<32><<<128, 256, 0, stream>>>(hnext, bn);
            k_bn_apply<32, false><<<(kN * 32 + 255) / 256, 256, 0, stream>>>(hnext, bn, gam, bet, out_h);
        }
    }

    k_pool<<<kG, 256, 0, stream>>>(out_h, batch, out_gemb);

    k_heads<<<1, 64, 0, stream>>>(out_gemb,
                                  (const float*)d_in[23], (const float*)d_in[24],
                                  (const float*)d_in[25], (const float*)d_in[26],
                                  (const float*)d_in[27], (const float*)d_in[28],
                                  (const float*)d_in[29], (const float*)d_in[30],
                                  out_eth, out_man);
}

// Round 2
// 1063.446 us; speedup vs baseline: 1.7545x; 1.7545x over previous
//
#include <hip/hip_runtime.h>
#include <math.h>

// Problem constants
constexpr int kN  = 50000;     // nodes
constexpr int kE  = 600000;    // raw edges
constexpr int kET = 650000;    // edges + self loops
constexpr int kG  = 50;        // graphs
constexpr int kH  = 4;         // heads

// ws layout (float offsets)
constexpr size_t OFF_HCUR  = 0;           // N*64
constexpr size_t OFF_HNEXT = 3200000;     // N*64
constexpr size_t OFF_HP    = 6400000;     // N*256
constexpr size_t OFF_ES    = 19200000;    // N*4
constexpr size_t OFF_ED    = 19400000;    // N*4
constexpr size_t OFF_ALPHA = 19600000;    // ET*4 (CSR-ordered edge weights)
constexpr size_t OFF_ROWPTR= 22200000;    // (N+1) ints
constexpr size_t OFF_CURSOR= 22260000;    // N ints (also used as counts)
constexpr size_t OFF_SRC   = 22320000;    // ET ints (CSR src list)
constexpr size_t OFF_BN    = 22980000;    // 2*64 floats

__device__ inline void edge_pair(const int* __restrict__ ei, int e, int& src, int& dst) {
    if (e < kE) { src = ei[e]; dst = ei[kE + e]; }
    else        { src = e - kE; dst = e - kE; }
}

// ---------------- CSR build (once per launch) ----------------
__global__ void k_hist(const int* __restrict__ ei, int* __restrict__ counts) {
    int e = blockIdx.x * blockDim.x + threadIdx.x;
    if (e >= kET) return;
    int src, dst;
    edge_pair(ei, e, src, dst);
    atomicAdd(&counts[dst], 1);
}

// single-block chunked scan: counts (aliased in cursor buf) -> rowptr (excl prefix, N+1)
// and cursor[i] = rowptr[i] (scatter cursors). Safe to alias: each idx read once, then written.
__global__ void k_scan(int* __restrict__ counts_cursor, int* __restrict__ rowptr) {
    __shared__ int sdata[1024];
    __shared__ int soffset;
    int tid = threadIdx.x;
    if (tid == 0) { soffset = 0; rowptr[0] = 0; }
    __syncthreads();
    for (int base = 0; base < kN; base += 1024) {
        int idx = base + tid;
        int val = (idx < kN) ? counts_cursor[idx] : 0;
        sdata[tid] = val;
        __syncthreads();
        for (int off = 1; off < 1024; off <<= 1) {
            int t = (tid >= off) ? sdata[tid - off] : 0;
            __syncthreads();
            sdata[tid] += t;
            __syncthreads();
        }
        int incl = sdata[tid];
        int offs = soffset;
        if (idx < kN) {
            rowptr[idx + 1] = offs + incl;
            counts_cursor[idx] = offs + incl - val;  // exclusive prefix = cursor start
        }
        __syncthreads();
        if (tid == 0) soffset += sdata[1023];
        __syncthreads();
    }
}

__global__ void k_scatter(const int* __restrict__ ei, int* __restrict__ cursor,
                          int* __restrict__ src_csr) {
    int e = blockIdx.x * blockDim.x + threadIdx.x;
    if (e >= kET) return;
    int src, dst;
    edge_pair(ei, e, src, dst);
    int pos = atomicAdd(&cursor[dst], 1);
    src_csr[pos] = src;
}

// ---------------- encoder ----------------
__global__ void k_encoder(const float* __restrict__ x, const float* __restrict__ w,
                          const float* __restrict__ b, float* __restrict__ h) {
    int i = blockIdx.x * blockDim.x + threadIdx.x;
    if (i >= kN * 64) return;
    int n = i >> 6, c = i & 63;
    float acc = b[c];
#pragma unroll
    for (int k = 0; k < 5; ++k) acc += x[n * 5 + k] * w[k * 64 + c];
    h[i] = acc;
}

// hp[n][j] = h[n][:64] @ W[:, j]; 4 rows per thread for W-load reuse
template <int HD>
__global__ void __launch_bounds__(256) k_linear(const float* __restrict__ h,
                                                const float* __restrict__ W,
                                                float* __restrict__ hp) {
    int i = blockIdx.x * blockDim.x + threadIdx.x;
    if (i >= (kN / 4) * HD) return;
    int j = i % HD;
    int n0 = (i / HD) * 4;
    const float* h0 = h + (size_t)n0 * 64;
    float a0 = 0.f, a1 = 0.f, a2 = 0.f, a3 = 0.f;
#pragma unroll 16
    for (int k = 0; k < 64; ++k) {
        float w = W[k * HD + j];
        a0 += h0[k] * w;
        a1 += h0[64 + k] * w;
        a2 += h0[128 + k] * w;
        a3 += h0[192 + k] * w;
    }
    hp[(size_t)n0 * HD + j]          = a0;
    hp[(size_t)(n0 + 1) * HD + j]    = a1;
    hp[(size_t)(n0 + 2) * HD + j]    = a2;
    hp[(size_t)(n0 + 3) * HD + j]    = a3;
}

// es[n][h], ed[n][h]
template <int DOUT>
__global__ void k_att(const float* __restrict__ hp, const float* __restrict__ a_s,
                      const float* __restrict__ a_d, float* __restrict__ es,
                      float* __restrict__ ed) {
    int i = blockIdx.x * blockDim.x + threadIdx.x;
    if (i >= kN * kH) return;
    int h = i & 3;
    const float* row = hp + (size_t)i * DOUT;
    float s1 = 0.f, s2 = 0.f;
#pragma unroll 8
    for (int c = 0; c < DOUT; ++c) {
        float v = row[c];
        s1 += v * a_s[h * DOUT + c];
        s2 += v * a_d[h * DOUT + c];
    }
    es[i] = s1;
    ed[i] = s2;
}

// per-(dst,head): online softmax over CSR in-edges, then write weights in CSR order.
// alpha[pos*4+h] = exp(v - m) * 0.25 / (s + 1e-16)
__global__ void k_softmax(const int* __restrict__ rowptr, const int* __restrict__ src_csr,
                          const float* __restrict__ es, const float* __restrict__ ed,
                          float* __restrict__ alpha) {
    int i = blockIdx.x * blockDim.x + threadIdx.x;
    if (i >= kN * kH) return;
    int dst = i >> 2, h = i & 3;
    int start = rowptr[dst], end = rowptr[dst + 1];
    float edv = ed[i];
    float m = -INFINITY, s = 0.f;
    for (int pos = start; pos < end; ++pos) {
        int src = src_csr[pos];
        float v = es[src * 4 + h] + edv;
        v = (v >= 0.f) ? v : 0.2f * v;
        float nm = fmaxf(m, v);
        s = s * __expf(m - nm) + __expf(v - nm);
        m = nm;
    }
    float inv = 0.25f / (s + 1e-16f);
    for (int pos = start; pos < end; ++pos) {
        int src = src_csr[pos];
        float v = es[src * 4 + h] + edv;
        v = (v >= 0.f) ? v : 0.2f * v;
        alpha[pos * 4 + h] = __expf(v - m) * inv;
    }
}

// one wave per dst; lanes = channels. hnext[dst][c] = sum_edges sum_h w*hp[src][h][c]
template <int DOUT>
__global__ void __launch_bounds__(256) k_agg(const int* __restrict__ rowptr,
                                             const int* __restrict__ src_csr,
                                             const float* __restrict__ alpha,
                                             const float* __restrict__ hp,
                                             float* __restrict__ hnext) {
    int wid = threadIdx.x >> 6;
    int lane = threadIdx.x & 63;
    int dst = blockIdx.x * 4 + wid;
    if (dst >= kN) return;
    int start = rowptr[dst], end = rowptr[dst + 1];
    const float4* al4 = (const float4*)alpha;

    if (DOUT == 64) {
        int c = lane;
        float acc = 0.f;
        for (int pos = start; pos < end; ++pos) {
            int src = src_csr[pos];
            float4 w = al4[pos];
            const float* base = hp + (size_t)src * 4 * 64 + c;
            acc += w.x * base[0] + w.y * base[64] + w.z * base[128] + w.w * base[192];
        }
        hnext[dst * 64 + c] = acc;
    } else {
        int c = lane & 31;
        int ks = lane >> 5;  // two half-waves process alternating edges
        float acc = 0.f;
        for (int pos = start + ks; pos < end; pos += 2) {
            int src = src_csr[pos];
            float4 w = al4[pos];
            const float* base = hp + (size_t)src * 4 * 32 + c;
            acc += w.x * base[0] + w.y * base[32] + w.z * base[64] + w.w * base[96];
        }
        acc += __shfl_xor(acc, 32);
        if (ks == 0) hnext[dst * 32 + c] = acc;
    }
}

// per-channel sum and sumsq over nodes
template <int DOUT>
__global__ void k_bn_stats(const float* __restrict__ h, float* __restrict__ bn) {
    constexpr int ROWS = 256 / DOUT;
    __shared__ float ls[256], lq[256];
    int c = threadIdx.x % DOUT;
    int r = threadIdx.x / DOUT;
    float s = 0.f, q = 0.f;
    for (int n = blockIdx.x * ROWS + r; n < kN; n += gridDim.x * ROWS) {
        float v = h[n * DOUT + c];
        s += v;
        q += v * v;
    }
    ls[threadIdx.x] = s;
    lq[threadIdx.x] = q;
    __syncthreads();
    if (r == 0) {
#pragma unroll
        for (int i = 1; i < ROWS; ++i) {
            s += ls[i * DOUT + c];
            q += lq[i * DOUT + c];
        }
        atomicAdd(&bn[c], s);
        atomicAdd(&bn[DOUT + c], q);
    }
}

template <int DOUT, bool RELU>
__global__ void k_bn_apply(const float* __restrict__ h, const float* __restrict__ bn,
                           const float* __restrict__ g, const float* __restrict__ be,
                           float* __restrict__ out) {
    int i = blockIdx.x * blockDim.x + threadIdx.x;
    if (i >= kN * DOUT) return;
    int c = i % DOUT;
    float mu = bn[c] * (1.f / kN);
    float var = bn[DOUT + c] * (1.f / kN) - mu * mu;
    float v = g[c] * (h[i] - mu) * rsqrtf(var + 1e-5f) + be[c];
    if (RELU) v = fmaxf(v, 0.f);
    out[i] = v;
}

// per-graph pooling: batch sorted -> binary-search boundaries, block reduce
__global__ void k_pool(const float* __restrict__ h, const int* __restrict__ batch,
                       float* __restrict__ gemb) {
    int g = blockIdx.x;
    int lo = 0, hi = kN;
    while (lo < hi) { int mid = (lo + hi) >> 1; if (batch[mid] < g) lo = mid + 1; else hi = mid; }
    int start = lo;
    lo = start; hi = kN;
    while (lo < hi) { int mid = (lo + hi) >> 1; if (batch[mid] < g + 1) lo = mid + 1; else hi = mid; }
    int end = lo;

    int c = threadIdx.x & 31, r = threadIdx.x >> 5;
    float sum = 0.f, mx = -INFINITY;
    for (int n = start + r; n < end; n += 8) {
        float v = h[n * 32 + c];
        sum += v;
        mx = fmaxf(mx, v);
    }
    __shared__ float ssum[256], smax[256];
    ssum[threadIdx.x] = sum;
    smax[threadIdx.x] = mx;
    __syncthreads();
    if (r == 0) {
#pragma unroll
        for (int i = 1; i < 8; ++i) {
            sum += ssum[i * 32 + c];
            mx = fmaxf(mx, smax[i * 32 + c]);
        }
        int cnt = end - start;
        float mean = sum / fmaxf((float)cnt, 1.f);
        if (cnt <= 0) mx = 0.f;
        gemb[g * 32 + c] = (mean + mx + sum) * (1.f / 3.f);
    }
}

__global__ void k_heads(const float* __restrict__ gemb, const float* __restrict__ ew1,
                        const float* __restrict__ eb1, const float* __restrict__ ew2,
                        const float* __restrict__ eb2, const float* __restrict__ mw1,
                        const float* __restrict__ mb1, const float* __restrict__ mw2,
                        const float* __restrict__ mb2, float* __restrict__ eth,
                        float* __restrict__ man) {
    int g = blockIdx.x * blockDim.x + threadIdx.x;
    if (g >= kG) return;
    const float* row = gemb + g * 32;
    float acc_e = eb2[0], acc_m = mb2[0];
#pragma unroll 4
    for (int j = 0; j < 16; ++j) {
        float he = eb1[j], hm = mb1[j];
        for (int k = 0; k < 32; ++k) {
            float v = row[k];
            he += v * ew1[k * 16 + j];
            hm += v * mw1[k * 16 + j];
        }
        acc_e += fmaxf(he, 0.f) * ew2[j];
        acc_m += fmaxf(hm, 0.f) * mw2[j];
    }
    eth[g] = 1.f / (1.f + expf(-acc_e));
    man[g] = 1.f / (1.f + expf(-acc_m));
}

extern "C" void kernel_launch(void* const* d_in, const int* in_sizes, int n_in,
                              void* d_out, int out_size, void* d_ws, size_t ws_size,
                              hipStream_t stream) {
    const float* x     = (const float*)d_in[0];
    const int*   ei    = (const int*)d_in[1];
    const int*   batch = (const int*)d_in[2];
    const float* enc_w = (const float*)d_in[3];
    const float* enc_b = (const float*)d_in[4];

    float* ws = (float*)d_ws;
    float* hcur   = ws + OFF_HCUR;
    float* hnext  = ws + OFF_HNEXT;
    float* hp     = ws + OFF_HP;
    float* es     = ws + OFF_ES;
    float* ed     = ws + OFF_ED;
    float* alpha  = ws + OFF_ALPHA;
    int*   rowptr = (int*)(ws + OFF_ROWPTR);
    int*   cursor = (int*)(ws + OFF_CURSOR);  // counts then scatter cursor
    int*   srcc   = (int*)(ws + OFF_SRC);
    float* bn     = ws + OFF_BN;

    float* out      = (float*)d_out;
    float* out_h    = out;                 // N*32
    float* out_gemb = out + 1600000;       // G*32
    float* out_eth  = out + 1601600;       // G
    float* out_man  = out + 1601650;       // G

    // ---- CSR build (once) ----
    hipMemsetAsync(cursor, 0, kN * sizeof(int), stream);
    k_hist<<<(kET + 255) / 256, 256, 0, stream>>>(ei, cursor);
    k_scan<<<1, 1024, 0, stream>>>(cursor, rowptr);
    k_scatter<<<(kET + 255) / 256, 256, 0, stream>>>(ei, cursor, srcc);

    k_encoder<<<(kN * 64 + 255) / 256, 256, 0, stream>>>(x, enc_w, enc_b, hcur);

    for (int l = 0; l < 3; ++l) {
        const int dout = (l == 2) ? 32 : 64;
        const float* W   = (const float*)d_in[5 + 6 * l];
        const float* a_s = (const float*)d_in[6 + 6 * l];
        const float* a_d = (const float*)d_in[7 + 6 * l];
        const float* gam = (const float*)d_in[9 + 6 * l];
        const float* bet = (const float*)d_in[10 + 6 * l];

        if (dout == 64) {
            k_linear<256><<<((kN / 4) * 256 + 255) / 256, 256, 0, stream>>>(hcur, W, hp);
            k_att<64><<<(kN * kH + 255) / 256, 256, 0, stream>>>(hp, a_s, a_d, es, ed);
        } else {
            k_linear<128><<<((kN / 4) * 128 + 255) / 256, 256, 0, stream>>>(hcur, W, hp);
            k_att<32><<<(kN * kH + 255) / 256, 256, 0, stream>>>(hp, a_s, a_d, es, ed);
        }

        k_softmax<<<(kN * kH + 255) / 256, 256, 0, stream>>>(rowptr, srcc, es, ed, alpha);

        hipMemsetAsync(bn, 0, 2 * 64 * sizeof(float), stream);

        if (dout == 64) {
            k_agg<64><<<kN / 4, 256, 0, stream>>>(rowptr, srcc, alpha, hp, hnext);
            k_bn_stats<64><<<128, 256, 0, stream>>>(hnext, bn);
            if (l < 2)
                k_bn_apply<64, true><<<(kN * 64 + 255) / 256, 256, 0, stream>>>(hnext, bn, gam, bet, hcur);
            else
                k_bn_apply<64, false><<<(kN * 64 + 255) / 256, 256, 0, stream>>>(hnext, bn, gam, bet, hcur);
        } else {
            k_agg<32><<<kN / 4, 256, 0, stream>>>(rowptr, srcc, alpha, hp, hnext);
            k_bn_stats<32><<<128, 256, 0, stream>>>(hnext, bn);
            k_bn_apply<32, false><<<(kN * 32 + 255) / 256, 256, 0, stream>>>(hnext, bn, gam, bet, out_h);
        }
    }

    k_pool<<<kG, 256, 0, stream>>>(out_h, batch, out_gemb);

    k_heads<<<1, 64, 0, stream>>>(out_gemb,
                                  (const float*)d_in[23], (const float*)d_in[24],
                                  (const float*)d_in[25], (const float*)d_in[26],
                                  (const float*)d_in[27], (const float*)d_in[28],
                                  (const float*)d_in[29], (const float*)d_in[30],
                                  out_eth, out_man);
}

// Round 3
// 793.614 us; speedup vs baseline: 2.3510x; 1.3400x over previous
//
#include <hip/hip_runtime.h>
#include <math.h>

// Problem constants
constexpr int kN  = 50000;     // nodes
constexpr int kE  = 600000;    // raw edges
constexpr int kET = 650000;    // edges + self loops
constexpr int kG  = 50;        // graphs
constexpr int kH  = 4;         // heads

// ws layout (float-slot offsets)
constexpr size_t OFF_HCUR   = 0;           // N*64 bf16  -> 1.6M float slots
constexpr size_t OFF_HNEXT  = 1600000;     // N*64 f32   -> 3.2M
constexpr size_t OFF_HP     = 4800000;     // N*256 bf16 -> 6.4M
constexpr size_t OFF_ES     = 11200000;    // N*4 f32
constexpr size_t OFF_ED     = 11400000;    // N*4 f32
constexpr size_t OFF_ALPHA  = 11600000;    // ET*4 f32 (scores then weights, CSR order)
constexpr size_t OFF_ROWPTR = 14200000;    // (N+1) ints
constexpr size_t OFF_CURSOR = 14260000;    // N ints
constexpr size_t OFF_SRC    = 14320000;    // ET ints
constexpr size_t OFF_WT     = 14970000;    // 256*64 bf16 -> 8192 float slots
constexpr size_t OFF_BN     = 14980000;    // 2*64 f32

typedef __bf16 bf16x8 __attribute__((ext_vector_type(8)));
typedef float  f32x4  __attribute__((ext_vector_type(4)));

__device__ inline ushort f2b(float f) {  // RNE float->bf16 bits
    unsigned u = __float_as_uint(f);
    return (ushort)((u + 0x7FFFu + ((u >> 16) & 1u)) >> 16);
}
__device__ inline float b2f(ushort u) {
    return __uint_as_float(((unsigned)u) << 16);
}

__device__ inline void edge_pair(const int* __restrict__ ei, int e, int& src, int& dst) {
    if (e < kE) { src = ei[e]; dst = ei[kE + e]; }
    else        { src = e - kE; dst = e - kE; }
}

// ---------------- CSR build (once per launch) ----------------
__global__ void k_hist(const int* __restrict__ ei, int* __restrict__ counts) {
    int e = blockIdx.x * blockDim.x + threadIdx.x;
    if (e >= kET) return;
    int src, dst;
    edge_pair(ei, e, src, dst);
    atomicAdd(&counts[dst], 1);
}

__global__ void k_scan(int* __restrict__ counts_cursor, int* __restrict__ rowptr) {
    __shared__ int sdata[1024];
    __shared__ int soffset;
    int tid = threadIdx.x;
    if (tid == 0) { soffset = 0; rowptr[0] = 0; }
    __syncthreads();
    for (int base = 0; base < kN; base += 1024) {
        int idx = base + tid;
        int val = (idx < kN) ? counts_cursor[idx] : 0;
        sdata[tid] = val;
        __syncthreads();
        for (int off = 1; off < 1024; off <<= 1) {
            int t = (tid >= off) ? sdata[tid - off] : 0;
            __syncthreads();
            sdata[tid] += t;
            __syncthreads();
        }
        int incl = sdata[tid];
        int offs = soffset;
        if (idx < kN) {
            rowptr[idx + 1] = offs + incl;
            counts_cursor[idx] = offs + incl - val;
        }
        __syncthreads();
        if (tid == 0) soffset += sdata[1023];
        __syncthreads();
    }
}

__global__ void k_scatter(const int* __restrict__ ei, int* __restrict__ cursor,
                          int* __restrict__ src_csr) {
    int e = blockIdx.x * blockDim.x + threadIdx.x;
    if (e >= kET) return;
    int src, dst;
    edge_pair(ei, e, src, dst);
    int pos = atomicAdd(&cursor[dst], 1);
    src_csr[pos] = src;
}

// ---------------- encoder: h0 = x @ enc_w + enc_b (bf16 out) ----------------
__global__ void k_encoder(const float* __restrict__ x, const float* __restrict__ w,
                          const float* __restrict__ b, ushort* __restrict__ h) {
    int i = blockIdx.x * blockDim.x + threadIdx.x;
    if (i >= kN * 64) return;
    int n = i >> 6, c = i & 63;
    float acc = b[c];
#pragma unroll
    for (int k = 0; k < 5; ++k) acc += x[n * 5 + k] * w[k * 64 + c];
    h[i] = f2b(acc);
}

// W[64][HD] f32 -> Wt[HD][64] bf16
__global__ void k_wt(const float* __restrict__ W, ushort* __restrict__ Wt, int HD) {
    int i = blockIdx.x * blockDim.x + threadIdx.x;
    if (i >= HD * 64) return;
    int n = i >> 6, k = i & 63;
    Wt[i] = f2b(W[k * HD + n]);
}

// MFMA GEMM: hp[N][HD] = h[N][64] @ W[64][HD], all bf16 storage, fp32 accum.
// One wave computes a 16x16 output tile via two 16x16x32 MFMAs.
template <int HD>
__global__ void __launch_bounds__(256) k_linear(const ushort* __restrict__ h,
                                                const ushort* __restrict__ Wt,
                                                ushort* __restrict__ hp) {
    constexpr int NT = HD / 16;
    int wave = (blockIdx.x * blockDim.x + threadIdx.x) >> 6;
    int lane = threadIdx.x & 63;
    int mtile = wave / NT;
    int ntile = wave - mtile * NT;
    int m0 = mtile * 16;
    int n0 = ntile * 16;
    if (m0 >= kN) return;

    int row = lane & 15;
    int k0  = (lane >> 4) * 8;

    bf16x8 a0 = *reinterpret_cast<const bf16x8*>(h + (size_t)(m0 + row) * 64 + k0);
    bf16x8 a1 = *reinterpret_cast<const bf16x8*>(h + (size_t)(m0 + row) * 64 + 32 + k0);
    bf16x8 b0 = *reinterpret_cast<const bf16x8*>(Wt + (size_t)(n0 + row) * 64 + k0);
    bf16x8 b1 = *reinterpret_cast<const bf16x8*>(Wt + (size_t)(n0 + row) * 64 + 32 + k0);

    f32x4 acc = {0.f, 0.f, 0.f, 0.f};
    acc = __builtin_amdgcn_mfma_f32_16x16x32_bf16(a0, b0, acc, 0, 0, 0);
    acc = __builtin_amdgcn_mfma_f32_16x16x32_bf16(a1, b1, acc, 0, 0, 0);

    int col = lane & 15;
    int r0  = (lane >> 4) * 4;
#pragma unroll
    for (int r = 0; r < 4; ++r) {
        hp[(size_t)(m0 + r0 + r) * HD + n0 + col] = f2b(acc[r]);
    }
}

// es[n][h], ed[n][h] from bf16 hp
template <int DOUT>
__global__ void k_att(const ushort* __restrict__ hp, const float* __restrict__ a_s,
                      const float* __restrict__ a_d, float* __restrict__ es,
                      float* __restrict__ ed) {
    int i = blockIdx.x * blockDim.x + threadIdx.x;
    if (i >= kN * kH) return;
    int h = i & 3;
    const uint4* row = reinterpret_cast<const uint4*>(hp + (size_t)i * DOUT);
    const float* as = a_s + h * DOUT;
    const float* ad = a_d + h * DOUT;
    float s1 = 0.f, s2 = 0.f;
#pragma unroll
    for (int c8 = 0; c8 < DOUT / 8; ++c8) {
        uint4 v = row[c8];
        unsigned uu[4] = {v.x, v.y, v.z, v.w};
#pragma unroll
        for (int q = 0; q < 4; ++q) {
            float lo = __uint_as_float(uu[q] << 16);
            float hi = __uint_as_float(uu[q] & 0xFFFF0000u);
            int c = c8 * 8 + q * 2;
            s1 += lo * as[c] + hi * as[c + 1];
            s2 += lo * ad[c] + hi * ad[c + 1];
        }
    }
    es[i] = s1;
    ed[i] = s2;
}

// per-(dst,head): pass1 computes scores (cached into alpha) + online max/sum,
// pass2 rewrites alpha with normalized weight * 0.25
__global__ void k_softmax(const int* __restrict__ rowptr, const int* __restrict__ src_csr,
                          const float* __restrict__ es, const float* __restrict__ ed,
                          float* __restrict__ alpha) {
    int i = blockIdx.x * blockDim.x + threadIdx.x;
    if (i >= kN * kH) return;
    int dst = i >> 2, h = i & 3;
    int start = rowptr[dst], end = rowptr[dst + 1];
    float edv = ed[i];
    float m = -INFINITY, s = 0.f;
    for (int pos = start; pos < end; ++pos) {
        int src = src_csr[pos];
        float v = es[src * 4 + h] + edv;
        v = (v >= 0.f) ? v : 0.2f * v;
        alpha[pos * 4 + h] = v;
        float nm = fmaxf(m, v);
        s = s * __expf(m - nm) + __expf(v - nm);
        m = nm;
    }
    float inv = 0.25f / (s + 1e-16f);
    for (int pos = start; pos < end; ++pos) {
        float v = alpha[pos * 4 + h];
        alpha[pos * 4 + h] = __expf(v - m) * inv;
    }
}

// one wave per dst; lanes = channels; bf16 hp gather
template <int DOUT>
__global__ void __launch_bounds__(256) k_agg(const int* __restrict__ rowptr,
                                             const int* __restrict__ src_csr,
                                             const float* __restrict__ alpha,
                                             const ushort* __restrict__ hp,
                                             float* __restrict__ hnext) {
    int wid = threadIdx.x >> 6;
    int lane = threadIdx.x & 63;
    int dst = blockIdx.x * 4 + wid;
    if (dst >= kN) return;
    int start = rowptr[dst], end = rowptr[dst + 1];
    const float4* al4 = (const float4*)alpha;

    if (DOUT == 64) {
        int c = lane;
        float acc = 0.f;
        for (int pos = start; pos < end; ++pos) {
            int src = src_csr[pos];
            float4 w = al4[pos];
            const ushort* base = hp + (size_t)src * 256 + c;
            acc += w.x * b2f(base[0]) + w.y * b2f(base[64]) +
                   w.z * b2f(base[128]) + w.w * b2f(base[192]);
        }
        hnext[dst * 64 + c] = acc;
    } else {
        int c = lane & 31;
        int ks = lane >> 5;
        float acc = 0.f;
        for (int pos = start + ks; pos < end; pos += 2) {
            int src = src_csr[pos];
            float4 w = al4[pos];
            const ushort* base = hp + (size_t)src * 128 + c;
            acc += w.x * b2f(base[0]) + w.y * b2f(base[32]) +
                   w.z * b2f(base[64]) + w.w * b2f(base[96]);
        }
        acc += __shfl_xor(acc, 32);
        if (ks == 0) hnext[dst * 32 + c] = acc;
    }
}

// per-channel sum and sumsq over nodes
template <int DOUT>
__global__ void k_bn_stats(const float* __restrict__ h, float* __restrict__ bn) {
    constexpr int ROWS = 256 / DOUT;
    __shared__ float ls[256], lq[256];
    int c = threadIdx.x % DOUT;
    int r = threadIdx.x / DOUT;
    float s = 0.f, q = 0.f;
    for (int n = blockIdx.x * ROWS + r; n < kN; n += gridDim.x * ROWS) {
        float v = h[n * DOUT + c];
        s += v;
        q += v * v;
    }
    ls[threadIdx.x] = s;
    lq[threadIdx.x] = q;
    __syncthreads();
    if (r == 0) {
#pragma unroll
        for (int i = 1; i < ROWS; ++i) {
            s += ls[i * DOUT + c];
            q += lq[i * DOUT + c];
        }
        atomicAdd(&bn[c], s);
        atomicAdd(&bn[DOUT + c], q);
    }
}

template <int DOUT, bool RELU, bool BF16OUT>
__global__ void k_bn_apply(const float* __restrict__ h, const float* __restrict__ bn,
                           const float* __restrict__ g, const float* __restrict__ be,
                           void* __restrict__ outp) {
    int i = blockIdx.x * blockDim.x + threadIdx.x;
    if (i >= kN * DOUT) return;
    int c = i % DOUT;
    float mu = bn[c] * (1.f / kN);
    float var = bn[DOUT + c] * (1.f / kN) - mu * mu;
    float v = g[c] * (h[i] - mu) * rsqrtf(var + 1e-5f) + be[c];
    if (RELU) v = fmaxf(v, 0.f);
    if (BF16OUT) ((ushort*)outp)[i] = f2b(v);
    else         ((float*)outp)[i] = v;
}

// per-graph pooling
__global__ void k_pool(const float* __restrict__ h, const int* __restrict__ batch,
                       float* __restrict__ gemb) {
    int g = blockIdx.x;
    int lo = 0, hi = kN;
    while (lo < hi) { int mid = (lo + hi) >> 1; if (batch[mid] < g) lo = mid + 1; else hi = mid; }
    int start = lo;
    lo = start; hi = kN;
    while (lo < hi) { int mid = (lo + hi) >> 1; if (batch[mid] < g + 1) lo = mid + 1; else hi = mid; }
    int end = lo;

    int c = threadIdx.x & 31, r = threadIdx.x >> 5;
    float sum = 0.f, mx = -INFINITY;
    for (int n = start + r; n < end; n += 8) {
        float v = h[n * 32 + c];
        sum += v;
        mx = fmaxf(mx, v);
    }
    __shared__ float ssum[256], smax[256];
    ssum[threadIdx.x] = sum;
    smax[threadIdx.x] = mx;
    __syncthreads();
    if (r == 0) {
#pragma unroll
        for (int i = 1; i < 8; ++i) {
            sum += ssum[i * 32 + c];
            mx = fmaxf(mx, smax[i * 32 + c]);
        }
        int cnt = end - start;
        float mean = sum / fmaxf((float)cnt, 1.f);
        if (cnt <= 0) mx = 0.f;
        gemb[g * 32 + c] = (mean + mx + sum) * (1.f / 3.f);
    }
}

__global__ void k_heads(const float* __restrict__ gemb, const float* __restrict__ ew1,
                        const float* __restrict__ eb1, const float* __restrict__ ew2,
                        const float* __restrict__ eb2, const float* __restrict__ mw1,
                        const float* __restrict__ mb1, const float* __restrict__ mw2,
                        const float* __restrict__ mb2, float* __restrict__ eth,
                        float* __restrict__ man) {
    int g = blockIdx.x * blockDim.x + threadIdx.x;
    if (g >= kG) return;
    const float* row = gemb + g * 32;
    float acc_e = eb2[0], acc_m = mb2[0];
#pragma unroll 4
    for (int j = 0; j < 16; ++j) {
        float he = eb1[j], hm = mb1[j];
        for (int k = 0; k < 32; ++k) {
            float v = row[k];
            he += v * ew1[k * 16 + j];
            hm += v * mw1[k * 16 + j];
        }
        acc_e += fmaxf(he, 0.f) * ew2[j];
        acc_m += fmaxf(hm, 0.f) * mw2[j];
    }
    eth[g] = 1.f / (1.f + expf(-acc_e));
    man[g] = 1.f / (1.f + expf(-acc_m));
}

extern "C" void kernel_launch(void* const* d_in, const int* in_sizes, int n_in,
                              void* d_out, int out_size, void* d_ws, size_t ws_size,
                              hipStream_t stream) {
    const float* x     = (const float*)d_in[0];
    const int*   ei    = (const int*)d_in[1];
    const int*   batch = (const int*)d_in[2];
    const float* enc_w = (const float*)d_in[3];
    const float* enc_b = (const float*)d_in[4];

    float* ws = (float*)d_ws;
    ushort* hcur  = (ushort*)(ws + OFF_HCUR);
    float*  hnext = ws + OFF_HNEXT;
    ushort* hp    = (ushort*)(ws + OFF_HP);
    float*  es    = ws + OFF_ES;
    float*  ed    = ws + OFF_ED;
    float*  alpha = ws + OFF_ALPHA;
    int*    rowptr= (int*)(ws + OFF_ROWPTR);
    int*    cursor= (int*)(ws + OFF_CURSOR);
    int*    srcc  = (int*)(ws + OFF_SRC);
    ushort* Wt    = (ushort*)(ws + OFF_WT);
    float*  bn    = ws + OFF_BN;

    float* out      = (float*)d_out;
    float* out_h    = out;                 // N*32
    float* out_gemb = out + 1600000;       // G*32
    float* out_eth  = out + 1601600;       // G
    float* out_man  = out + 1601650;       // G

    // ---- CSR build (once) ----
    hipMemsetAsync(cursor, 0, kN * sizeof(int), stream);
    k_hist<<<(kET + 255) / 256, 256, 0, stream>>>(ei, cursor);
    k_scan<<<1, 1024, 0, stream>>>(cursor, rowptr);
    k_scatter<<<(kET + 255) / 256, 256, 0, stream>>>(ei, cursor, srcc);

    k_encoder<<<(kN * 64 + 255) / 256, 256, 0, stream>>>(x, enc_w, enc_b, hcur);

    for (int l = 0; l < 3; ++l) {
        const int dout = (l == 2) ? 32 : 64;
        const int HD = 4 * dout;
        const float* W   = (const float*)d_in[5 + 6 * l];
        const float* a_s = (const float*)d_in[6 + 6 * l];
        const float* a_d = (const float*)d_in[7 + 6 * l];
        const float* gam = (const float*)d_in[9 + 6 * l];
        const float* bet = (const float*)d_in[10 + 6 * l];

        k_wt<<<(HD * 64 + 255) / 256, 256, 0, stream>>>(W, Wt, HD);

        if (dout == 64) {
            // 3125 m-tiles * 16 n-tiles = 50000 waves; 4 waves/block
            k_linear<256><<<12500, 256, 0, stream>>>(hcur, Wt, hp);
            k_att<64><<<(kN * kH + 255) / 256, 256, 0, stream>>>(hp, a_s, a_d, es, ed);
        } else {
            // 3125 * 8 = 25000 waves
            k_linear<128><<<6250, 256, 0, stream>>>(hcur, Wt, hp);
            k_att<32><<<(kN * kH + 255) / 256, 256, 0, stream>>>(hp, a_s, a_d, es, ed);
        }

        k_softmax<<<(kN * kH + 255) / 256, 256, 0, stream>>>(rowptr, srcc, es, ed, alpha);

        hipMemsetAsync(bn, 0, 2 * 64 * sizeof(float), stream);

        if (dout == 64) {
            k_agg<64><<<kN / 4, 256, 0, stream>>>(rowptr, srcc, alpha, hp, hnext);
            k_bn_stats<64><<<128, 256, 0, stream>>>(hnext, bn);
            if (l < 2)
                k_bn_apply<64, true, true><<<(kN * 64 + 255) / 256, 256, 0, stream>>>(hnext, bn, gam, bet, hcur);
            else
                k_bn_apply<64, false, true><<<(kN * 64 + 255) / 256, 256, 0, stream>>>(hnext, bn, gam, bet, hcur);
        } else {
            k_agg<32><<<kN / 4, 256, 0, stream>>>(rowptr, srcc, alpha, hp, hnext);
            k_bn_stats<32><<<128, 256, 0, stream>>>(hnext, bn);
            k_bn_apply<32, false, false><<<(kN * 32 + 255) / 256, 256, 0, stream>>>(hnext, bn, gam, bet, out_h);
        }
    }

    k_pool<<<kG, 256, 0, stream>>>(out_h, batch, out_gemb);

    k_heads<<<1, 64, 0, stream>>>(out_gemb,
                                  (const float*)d_in[23], (const float*)d_in[24],
                                  (const float*)d_in[25], (const float*)d_in[26],
                                  (const float*)d_in[27], (const float*)d_in[28],
                                  (const float*)d_in[29], (const float*)d_in[30],
                                  out_eth, out_man);
}

// Round 4
// 707.718 us; speedup vs baseline: 2.6364x; 1.1214x over previous
//
#include <hip/hip_runtime.h>
#include <math.h>

// Problem constants
constexpr int kN  = 50000;     // nodes
constexpr int kE  = 600000;    // raw edges
constexpr int kET = 650000;    // edges + self loops
constexpr int kG  = 50;        // graphs
constexpr int kH  = 4;         // heads

// ws layout (float-slot offsets)
constexpr size_t OFF_HCUR   = 0;           // N*64 bf16  -> 1.6M float slots
constexpr size_t OFF_HNEXT  = 1600000;     // N*64 f32   -> 3.2M
constexpr size_t OFF_HP     = 4800000;     // N*256 bf16 -> 6.4M
constexpr size_t OFF_ES     = 11200000;    // N*4 f32
constexpr size_t OFF_ED     = 11400000;    // N*4 f32
constexpr size_t OFF_ALPHA  = 11600000;    // ET*4 f32 (scores then weights, CSR order)
constexpr size_t OFF_ROWPTR = 14200000;    // (N+1) ints
constexpr size_t OFF_CURSOR = 14260000;    // N ints
constexpr size_t OFF_SRC    = 14320000;    // ET ints
constexpr size_t OFF_WT     = 14970000;    // 256*64 bf16 -> 8192 float slots
constexpr size_t OFF_BN     = 14980000;    // 2*64 f32
constexpr size_t OFF_PART   = 14990000;    // 64 ints (scan partials)

constexpr int kScanBlocks = (kN + 1023) / 1024;  // 49

typedef __bf16 bf16x8 __attribute__((ext_vector_type(8)));
typedef float  f32x4  __attribute__((ext_vector_type(4)));

__device__ inline ushort f2b(float f) {  // RNE float->bf16 bits
    unsigned u = __float_as_uint(f);
    return (ushort)((u + 0x7FFFu + ((u >> 16) & 1u)) >> 16);
}
__device__ inline float b2f(ushort u) {
    return __uint_as_float(((unsigned)u) << 16);
}

__device__ inline void edge_pair(const int* __restrict__ ei, int e, int& src, int& dst) {
    if (e < kE) { src = ei[e]; dst = ei[kE + e]; }
    else        { src = e - kE; dst = e - kE; }
}

// ---------------- CSR build (once per launch) ----------------
__global__ void k_hist(const int* __restrict__ ei, int* __restrict__ counts) {
    int e = blockIdx.x * blockDim.x + threadIdx.x;
    if (e >= kET) return;
    int src, dst;
    edge_pair(ei, e, src, dst);
    atomicAdd(&counts[dst], 1);
}

// two-level scan, stage 1: per-block inclusive scan (wave shfl + LDS wave sums)
__global__ void __launch_bounds__(1024) k_scan_local(const int* __restrict__ counts,
                                                     int* __restrict__ rowptr,
                                                     int* __restrict__ partials) {
    int tid = threadIdx.x;
    int idx = blockIdx.x * 1024 + tid;
    int val = (idx < kN) ? counts[idx] : 0;
    int lane = tid & 63, w = tid >> 6;
    int x = val;
#pragma unroll
    for (int off = 1; off < 64; off <<= 1) {
        int t = __shfl_up(x, off);
        if (lane >= off) x += t;
    }
    __shared__ int wsum[16];
    if (lane == 63) wsum[w] = x;
    __syncthreads();
    if (w == 0 && lane < 16) {
        int y = wsum[lane];
#pragma unroll
        for (int off = 1; off < 16; off <<= 1) {
            int t = __shfl_up(y, off);
            if (lane >= off) y += t;
        }
        wsum[lane] = y;
    }
    __syncthreads();
    int incl = x + (w > 0 ? wsum[w - 1] : 0);
    if (idx < kN) rowptr[idx + 1] = incl;       // local inclusive (temp)
    if (tid == 1023) partials[blockIdx.x] = incl;  // block total
}

// stage 2: one wave exclusive-scans the block totals
__global__ void k_scan_part(int* __restrict__ partials) {
    int lane = threadIdx.x;
    int v = (lane < kScanBlocks) ? partials[lane] : 0;
    int x = v;
#pragma unroll
    for (int off = 1; off < 64; off <<= 1) {
        int t = __shfl_up(x, off);
        if (lane >= off) x += t;
    }
    if (lane < kScanBlocks) partials[lane] = x - v;  // exclusive
}

// stage 3: add block offsets -> final rowptr; cursor = exclusive prefix
__global__ void __launch_bounds__(1024) k_scan_add(int* __restrict__ cursor,
                                                   int* __restrict__ rowptr,
                                                   const int* __restrict__ partials) {
    int idx = blockIdx.x * 1024 + threadIdx.x;
    if (idx >= kN) return;
    int incl = rowptr[idx + 1] + partials[blockIdx.x];
    rowptr[idx + 1] = incl;
    int val = cursor[idx];           // still holds counts
    cursor[idx] = incl - val;        // scatter cursor start
    if (idx == 0) rowptr[0] = 0;
}

__global__ void k_scatter(const int* __restrict__ ei, int* __restrict__ cursor,
                          int* __restrict__ src_csr) {
    int e = blockIdx.x * blockDim.x + threadIdx.x;
    if (e >= kET) return;
    int src, dst;
    edge_pair(ei, e, src, dst);
    int pos = atomicAdd(&cursor[dst], 1);
    src_csr[pos] = src;
}

// ---------------- encoder: h0 = x @ enc_w + enc_b (bf16 out) ----------------
__global__ void k_encoder(const float* __restrict__ x, const float* __restrict__ w,
                          const float* __restrict__ b, ushort* __restrict__ h) {
    int i = blockIdx.x * blockDim.x + threadIdx.x;
    if (i >= kN * 64) return;
    int n = i >> 6, c = i & 63;
    float acc = b[c];
#pragma unroll
    for (int k = 0; k < 5; ++k) acc += x[n * 5 + k] * w[k * 64 + c];
    h[i] = f2b(acc);
}

// W[64][HD] f32 -> Wt[HD][64] bf16
__global__ void k_wt(const float* __restrict__ W, ushort* __restrict__ Wt, int HD) {
    int i = blockIdx.x * blockDim.x + threadIdx.x;
    if (i >= HD * 64) return;
    int n = i >> 6, k = i & 63;
    Wt[i] = f2b(W[k * HD + n]);
}

// MFMA GEMM: hp[N][HD] = h[N][64] @ W[64][HD], bf16 storage, fp32 accum.
template <int HD>
__global__ void __launch_bounds__(256) k_linear(const ushort* __restrict__ h,
                                                const ushort* __restrict__ Wt,
                                                ushort* __restrict__ hp) {
    constexpr int NT = HD / 16;
    int wave = (blockIdx.x * blockDim.x + threadIdx.x) >> 6;
    int lane = threadIdx.x & 63;
    int mtile = wave / NT;
    int ntile = wave - mtile * NT;
    int m0 = mtile * 16;
    int n0 = ntile * 16;
    if (m0 >= kN) return;

    int row = lane & 15;
    int k0  = (lane >> 4) * 8;

    bf16x8 a0 = *reinterpret_cast<const bf16x8*>(h + (size_t)(m0 + row) * 64 + k0);
    bf16x8 a1 = *reinterpret_cast<const bf16x8*>(h + (size_t)(m0 + row) * 64 + 32 + k0);
    bf16x8 b0 = *reinterpret_cast<const bf16x8*>(Wt + (size_t)(n0 + row) * 64 + k0);
    bf16x8 b1 = *reinterpret_cast<const bf16x8*>(Wt + (size_t)(n0 + row) * 64 + 32 + k0);

    f32x4 acc = {0.f, 0.f, 0.f, 0.f};
    acc = __builtin_amdgcn_mfma_f32_16x16x32_bf16(a0, b0, acc, 0, 0, 0);
    acc = __builtin_amdgcn_mfma_f32_16x16x32_bf16(a1, b1, acc, 0, 0, 0);

    int col = lane & 15;
    int r0  = (lane >> 4) * 4;
#pragma unroll
    for (int r = 0; r < 4; ++r) {
        hp[(size_t)(m0 + r0 + r) * HD + n0 + col] = f2b(acc[r]);
    }
}

// es[n][h], ed[n][h] from bf16 hp
template <int DOUT>
__global__ void k_att(const ushort* __restrict__ hp, const float* __restrict__ a_s,
                      const float* __restrict__ a_d, float* __restrict__ es,
                      float* __restrict__ ed) {
    int i = blockIdx.x * blockDim.x + threadIdx.x;
    if (i >= kN * kH) return;
    int h = i & 3;
    const uint4* row = reinterpret_cast<const uint4*>(hp + (size_t)i * DOUT);
    const float* as = a_s + h * DOUT;
    const float* ad = a_d + h * DOUT;
    float s1 = 0.f, s2 = 0.f;
#pragma unroll
    for (int c8 = 0; c8 < DOUT / 8; ++c8) {
        uint4 v = row[c8];
        unsigned uu[4] = {v.x, v.y, v.z, v.w};
#pragma unroll
        for (int q = 0; q < 4; ++q) {
            float lo = __uint_as_float(uu[q] << 16);
            float hi = __uint_as_float(uu[q] & 0xFFFF0000u);
            int c = c8 * 8 + q * 2;
            s1 += lo * as[c] + hi * as[c + 1];
            s2 += lo * ad[c] + hi * ad[c + 1];
        }
    }
    es[i] = s1;
    ed[i] = s2;
}

// per-(dst,head): pass1 computes scores (cached into alpha) + online max/sum,
// pass2 rewrites alpha with normalized weight * 0.25
__global__ void k_softmax(const int* __restrict__ rowptr, const int* __restrict__ src_csr,
                          const float* __restrict__ es, const float* __restrict__ ed,
                          float* __restrict__ alpha) {
    int i = blockIdx.x * blockDim.x + threadIdx.x;
    if (i >= kN * kH) return;
    int dst = i >> 2, h = i & 3;
    int start = rowptr[dst], end = rowptr[dst + 1];
    float edv = ed[i];
    float m = -INFINITY, s = 0.f;
    for (int pos = start; pos < end; ++pos) {
        int src = src_csr[pos];
        float v = es[src * 4 + h] + edv;
        v = (v >= 0.f) ? v : 0.2f * v;
        alpha[pos * 4 + h] = v;
        float nm = fmaxf(m, v);
        s = s * __expf(m - nm) + __expf(v - nm);
        m = nm;
    }
    float inv = 0.25f / (s + 1e-16f);
    for (int pos = start; pos < end; ++pos) {
        float v = alpha[pos * 4 + h];
        alpha[pos * 4 + h] = __expf(v - m) * inv;
    }
}

// one wave per dst; lanes = channels; bf16 hp gather
template <int DOUT>
__global__ void __launch_bounds__(256) k_agg(const int* __restrict__ rowptr,
                                             const int* __restrict__ src_csr,
                                             const float* __restrict__ alpha,
                                             const ushort* __restrict__ hp,
                                             float* __restrict__ hnext) {
    int wid = threadIdx.x >> 6;
    int lane = threadIdx.x & 63;
    int dst = blockIdx.x * 4 + wid;
    if (dst >= kN) return;
    int start = rowptr[dst], end = rowptr[dst + 1];
    const float4* al4 = (const float4*)alpha;

    if (DOUT == 64) {
        int c = lane;
        float acc = 0.f;
        for (int pos = start; pos < end; ++pos) {
            int src = src_csr[pos];
            float4 w = al4[pos];
            const ushort* base = hp + (size_t)src * 256 + c;
            acc += w.x * b2f(base[0]) + w.y * b2f(base[64]) +
                   w.z * b2f(base[128]) + w.w * b2f(base[192]);
        }
        hnext[dst * 64 + c] = acc;
    } else {
        int c = lane & 31;
        int ks = lane >> 5;
        float acc = 0.f;
        for (int pos = start + ks; pos < end; pos += 2) {
            int src = src_csr[pos];
            float4 w = al4[pos];
            const ushort* base = hp + (size_t)src * 128 + c;
            acc += w.x * b2f(base[0]) + w.y * b2f(base[32]) +
                   w.z * b2f(base[64]) + w.w * b2f(base[96]);
        }
        acc += __shfl_xor(acc, 32);
        if (ks == 0) hnext[dst * 32 + c] = acc;
    }
}

// per-channel sum and sumsq over nodes
template <int DOUT>
__global__ void k_bn_stats(const float* __restrict__ h, float* __restrict__ bn) {
    constexpr int ROWS = 256 / DOUT;
    __shared__ float ls[256], lq[256];
    int c = threadIdx.x % DOUT;
    int r = threadIdx.x / DOUT;
    float s = 0.f, q = 0.f;
    for (int n = blockIdx.x * ROWS + r; n < kN; n += gridDim.x * ROWS) {
        float v = h[n * DOUT + c];
        s += v;
        q += v * v;
    }
    ls[threadIdx.x] = s;
    lq[threadIdx.x] = q;
    __syncthreads();
    if (r == 0) {
#pragma unroll
        for (int i = 1; i < ROWS; ++i) {
            s += ls[i * DOUT + c];
            q += lq[i * DOUT + c];
        }
        atomicAdd(&bn[c], s);
        atomicAdd(&bn[DOUT + c], q);
    }
}

template <int DOUT, bool RELU, bool BF16OUT>
__global__ void k_bn_apply(const float* __restrict__ h, const float* __restrict__ bn,
                           const float* __restrict__ g, const float* __restrict__ be,
                           void* __restrict__ outp) {
    int i = blockIdx.x * blockDim.x + threadIdx.x;
    if (i >= kN * DOUT) return;
    int c = i % DOUT;
    float mu = bn[c] * (1.f / kN);
    float var = bn[DOUT + c] * (1.f / kN) - mu * mu;
    float v = g[c] * (h[i] - mu) * rsqrtf(var + 1e-5f) + be[c];
    if (RELU) v = fmaxf(v, 0.f);
    if (BF16OUT) ((ushort*)outp)[i] = f2b(v);
    else         ((float*)outp)[i] = v;
}

// per-graph pooling
__global__ void k_pool(const float* __restrict__ h, const int* __restrict__ batch,
                       float* __restrict__ gemb) {
    int g = blockIdx.x;
    int lo = 0, hi = kN;
    while (lo < hi) { int mid = (lo + hi) >> 1; if (batch[mid] < g) lo = mid + 1; else hi = mid; }
    int start = lo;
    lo = start; hi = kN;
    while (lo < hi) { int mid = (lo + hi) >> 1; if (batch[mid] < g + 1) lo = mid + 1; else hi = mid; }
    int end = lo;

    int c = threadIdx.x & 31, r = threadIdx.x >> 5;
    float sum = 0.f, mx = -INFINITY;
    for (int n = start + r; n < end; n += 8) {
        float v = h[n * 32 + c];
        sum += v;
        mx = fmaxf(mx, v);
    }
    __shared__ float ssum[256], smax[256];
    ssum[threadIdx.x] = sum;
    smax[threadIdx.x] = mx;
    __syncthreads();
    if (r == 0) {
#pragma unroll
        for (int i = 1; i < 8; ++i) {
            sum += ssum[i * 32 + c];
            mx = fmaxf(mx, smax[i * 32 + c]);
        }
        int cnt = end - start;
        float mean = sum / fmaxf((float)cnt, 1.f);
        if (cnt <= 0) mx = 0.f;
        gemb[g * 32 + c] = (mean + mx + sum) * (1.f / 3.f);
    }
}

__global__ void k_heads(const float* __restrict__ gemb, const float* __restrict__ ew1,
                        const float* __restrict__ eb1, const float* __restrict__ ew2,
                        const float* __restrict__ eb2, const float* __restrict__ mw1,
                        const float* __restrict__ mb1, const float* __restrict__ mw2,
                        const float* __restrict__ mb2, float* __restrict__ eth,
                        float* __restrict__ man) {
    int g = blockIdx.x * blockDim.x + threadIdx.x;
    if (g >= kG) return;
    const float* row = gemb + g * 32;
    float acc_e = eb2[0], acc_m = mb2[0];
#pragma unroll 4
    for (int j = 0; j < 16; ++j) {
        float he = eb1[j], hm = mb1[j];
        for (int k = 0; k < 32; ++k) {
            float v = row[k];
            he += v * ew1[k * 16 + j];
            hm += v * mw1[k * 16 + j];
        }
        acc_e += fmaxf(he, 0.f) * ew2[j];
        acc_m += fmaxf(hm, 0.f) * mw2[j];
    }
    eth[g] = 1.f / (1.f + expf(-acc_e));
    man[g] = 1.f / (1.f + expf(-acc_m));
}

extern "C" void kernel_launch(void* const* d_in, const int* in_sizes, int n_in,
                              void* d_out, int out_size, void* d_ws, size_t ws_size,
                              hipStream_t stream) {
    const float* x     = (const float*)d_in[0];
    const int*   ei    = (const int*)d_in[1];
    const int*   batch = (const int*)d_in[2];
    const float* enc_w = (const float*)d_in[3];
    const float* enc_b = (const float*)d_in[4];

    float* ws = (float*)d_ws;
    ushort* hcur  = (ushort*)(ws + OFF_HCUR);
    float*  hnext = ws + OFF_HNEXT;
    ushort* hp    = (ushort*)(ws + OFF_HP);
    float*  es    = ws + OFF_ES;
    float*  ed    = ws + OFF_ED;
    float*  alpha = ws + OFF_ALPHA;
    int*    rowptr= (int*)(ws + OFF_ROWPTR);
    int*    cursor= (int*)(ws + OFF_CURSOR);
    int*    srcc  = (int*)(ws + OFF_SRC);
    ushort* Wt    = (ushort*)(ws + OFF_WT);
    float*  bn    = ws + OFF_BN;
    int*    part  = (int*)(ws + OFF_PART);

    float* out      = (float*)d_out;
    float* out_h    = out;                 // N*32
    float* out_gemb = out + 1600000;       // G*32
    float* out_eth  = out + 1601600;       // G
    float* out_man  = out + 1601650;       // G

    // ---- CSR build (once) ----
    hipMemsetAsync(cursor, 0, kN * sizeof(int), stream);
    k_hist<<<(kET + 255) / 256, 256, 0, stream>>>(ei, cursor);
    k_scan_local<<<kScanBlocks, 1024, 0, stream>>>(cursor, rowptr, part);
    k_scan_part<<<1, 64, 0, stream>>>(part);
    k_scan_add<<<kScanBlocks, 1024, 0, stream>>>(cursor, rowptr, part);
    k_scatter<<<(kET + 255) / 256, 256, 0, stream>>>(ei, cursor, srcc);

    k_encoder<<<(kN * 64 + 255) / 256, 256, 0, stream>>>(x, enc_w, enc_b, hcur);

    for (int l = 0; l < 3; ++l) {
        const int dout = (l == 2) ? 32 : 64;
        const int HD = 4 * dout;
        const float* W   = (const float*)d_in[5 + 6 * l];
        const float* a_s = (const float*)d_in[6 + 6 * l];
        const float* a_d = (const float*)d_in[7 + 6 * l];
        const float* gam = (const float*)d_in[9 + 6 * l];
        const float* bet = (const float*)d_in[10 + 6 * l];

        k_wt<<<(HD * 64 + 255) / 256, 256, 0, stream>>>(W, Wt, HD);

        if (dout == 64) {
            k_linear<256><<<12500, 256, 0, stream>>>(hcur, Wt, hp);
            k_att<64><<<(kN * kH + 255) / 256, 256, 0, stream>>>(hp, a_s, a_d, es, ed);
        } else {
            k_linear<128><<<6250, 256, 0, stream>>>(hcur, Wt, hp);
            k_att<32><<<(kN * kH + 255) / 256, 256, 0, stream>>>(hp, a_s, a_d, es, ed);
        }

        k_softmax<<<(kN * kH + 255) / 256, 256, 0, stream>>>(rowptr, srcc, es, ed, alpha);

        hipMemsetAsync(bn, 0, 2 * 64 * sizeof(float), stream);

        if (dout == 64) {
            k_agg<64><<<kN / 4, 256, 0, stream>>>(rowptr, srcc, alpha, hp, hnext);
            k_bn_stats<64><<<128, 256, 0, stream>>>(hnext, bn);
            if (l < 2)
                k_bn_apply<64, true, true><<<(kN * 64 + 255) / 256, 256, 0, stream>>>(hnext, bn, gam, bet, hcur);
            else
                k_bn_apply<64, false, true><<<(kN * 64 + 255) / 256, 256, 0, stream>>>(hnext, bn, gam, bet, hcur);
        } else {
            k_agg<32><<<kN / 4, 256, 0, stream>>>(rowptr, srcc, alpha, hp, hnext);
            k_bn_stats<32><<<128, 256, 0, stream>>>(hnext, bn);
            k_bn_apply<32, false, false><<<(kN * 32 + 255) / 256, 256, 0, stream>>>(hnext, bn, gam, bet, out_h);
        }
    }

    k_pool<<<kG, 256, 0, stream>>>(out_h, batch, out_gemb);

    k_heads<<<1, 64, 0, stream>>>(out_gemb,
                                  (const float*)d_in[23], (const float*)d_in[24],
                                  (const float*)d_in[25], (const float*)d_in[26],
                                  (const float*)d_in[27], (const float*)d_in[28],
                                  (const float*)d_in[29], (const float*)d_in[30],
                                  out_eth, out_man);
}